// Round 1
// baseline (300.667 us; speedup 1.0000x reference)
//
#include <hip/hip_runtime.h>
#include <hip/hip_bf16.h>

// ---------------------------------------------------------------------------
// SingleLayerMoE: T=1024 tokens, H=1024, E=8 experts, I=1024, top-2 routing.
// Sparse dispatch: router -> per-expert token lists -> per-expert MFMA GEMMs
// (gate_up + GLU, then down * router_weight) -> combine.
// ---------------------------------------------------------------------------

typedef unsigned short u16;
typedef __attribute__((ext_vector_type(8))) __bf16 bf16x8;
typedef __attribute__((ext_vector_type(4))) float f32x4;

#define T_TOK 1024
#define H_DIM 1024
#define E_NUM 8
#define I_DIM 1024
#define ALPHA 1.702f
#define LIMIT 7.0f

// round-to-nearest-even fp32 -> bf16 (no NaN in this workload)
__device__ __forceinline__ u16 f2bf(float f) {
    unsigned u = __builtin_bit_cast(unsigned, f);
    u = (u + 0x7FFFu + ((u >> 16) & 1u)) >> 16;
    return (u16)u;
}

__device__ __forceinline__ f32x4 mfma16(bf16x8 a, bf16x8 b, f32x4 c) {
    return __builtin_amdgcn_mfma_f32_16x16x32_bf16(a, b, c, 0, 0, 0);
}

// --------------------------- K0: zero counters ------------------------------
__global__ void k_zero(int* counts) {
    if (threadIdx.x < E_NUM) counts[threadIdx.x] = 0;
}

// --------------------------- K1: router + dispatch + x->bf16 ----------------
// one block (256 thr) per token
__global__ __launch_bounds__(256) void k_router(
    const float* __restrict__ x, const float* __restrict__ rw,
    const float* __restrict__ rb,
    int* __restrict__ counts, int* __restrict__ tk_e, int* __restrict__ tk_slot,
    float* __restrict__ tk_w, int* __restrict__ tok_list,
    float* __restrict__ w_list, u16* __restrict__ xb)
{
    const int t = blockIdx.x;
    const int tid = threadIdx.x;
    const float4 xv = *(const float4*)(x + (size_t)t * H_DIM + tid * 4);

    // store bf16 copy of the hidden state (A operand for gate_up GEMM)
    unsigned lo = (unsigned)f2bf(xv.x) | ((unsigned)f2bf(xv.y) << 16);
    unsigned hi = (unsigned)f2bf(xv.z) | ((unsigned)f2bf(xv.w) << 16);
    *(uint2*)(xb + (size_t)t * H_DIM + tid * 4) = make_uint2(lo, hi);

    // partial logits for all 8 experts (fp32 — must match np top-k closely)
    float p[E_NUM];
#pragma unroll
    for (int e = 0; e < E_NUM; ++e) {
        const float4 wv = *(const float4*)(rw + e * H_DIM + tid * 4);
        p[e] = xv.x * wv.x + xv.y * wv.y + xv.z * wv.z + xv.w * wv.w;
    }
#pragma unroll
    for (int off = 32; off; off >>= 1) {
#pragma unroll
        for (int e = 0; e < E_NUM; ++e) p[e] += __shfl_down(p[e], off, 64);
    }
    __shared__ float red[4][E_NUM];
    const int lane = tid & 63, wvid = tid >> 6;
    if (lane == 0) {
#pragma unroll
        for (int e = 0; e < E_NUM; ++e) red[wvid][e] = p[e];
    }
    __syncthreads();
    if (tid == 0) {
        float lg[E_NUM];
#pragma unroll
        for (int e = 0; e < E_NUM; ++e)
            lg[e] = red[0][e] + red[1][e] + red[2][e] + red[3][e] + rb[e];
        // top-2 (first index wins ties, matching lax.top_k)
        float m1 = -1e30f, m2 = -1e30f; int i1 = 0, i2 = 0;
#pragma unroll
        for (int e = 0; e < E_NUM; ++e) {
            float l = lg[e];
            if (l > m1) { m2 = m1; i2 = i1; m1 = l; i1 = e; }
            else if (l > m2) { m2 = l; i2 = e; }
        }
        float s = 0.f;
#pragma unroll
        for (int e = 0; e < E_NUM; ++e) s += __expf(lg[e] - m1);
        const float w0 = __expf(m1 - m1) / s;
        const float w1 = __expf(m2 - m1) / s;
        int ee[2] = { i1, i2 };
        float ww[2] = { w0, w1 };
#pragma unroll
        for (int k = 0; k < 2; ++k) {
            int e = ee[k];
            int slot = atomicAdd(&counts[e], 1);
            tok_list[e * T_TOK + slot] = t;
            w_list[e * T_TOK + slot] = ww[k];
            tk_e[t * 2 + k] = e;
            tk_slot[t * 2 + k] = slot;
            tk_w[t * 2 + k] = ww[k];
        }
    }
}

// --------------------------- K2: prefix over 8 counts -----------------------
__global__ void k_prefix(const int* __restrict__ counts, int* __restrict__ ebase) {
    if (threadIdx.x == 0) {
        int a = 0;
        for (int e = 0; e < E_NUM; ++e) { ebase[e] = a; a += counts[e]; }
    }
}

// --------------------------- K3: gate_up GEMM + GLU -------------------------
// grid (16 col-strips of 64 act cols, 8 m-tiles of 128 rows, 8 experts)
__global__ __launch_bounds__(256, 2) void k_gateup(
    const float* __restrict__ gup, const float* __restrict__ gub,
    const int* __restrict__ counts, const int* __restrict__ ebase,
    const int* __restrict__ tok_list, const u16* __restrict__ xb,
    u16* __restrict__ act)
{
    const int e = blockIdx.z;
    const int cnt = counts[e];
    const int m0 = blockIdx.y * 128;
    if (m0 >= cnt) return;
    const int n0 = blockIdx.x * 64;
    const int abase = ebase[e];
    const int tid = threadIdx.x;

    // +8 shorts of row padding: breaks the 64B-stride 8-way bank conflict on
    // the b128 fragment reads (stride 80B -> banks fully spread).
    __shared__ __align__(16) u16 As[128 * 40];
    __shared__ __align__(16) u16 Bs[128 * 40]; // cols 0..63 gate, 64..127 up

    // A staging: thread -> (row, 16-elem k chunk)
    const int am = tid >> 1, akq = tid & 1;
    const int aslot = m0 + am;
    const int atok = (aslot < cnt) ? tok_list[e * T_TOK + aslot] : 0;
    const u16* arow = xb + (size_t)atok * H_DIM + akq * 16;
    u16* asdst = &As[am * 40 + akq * 16];

    // B staging: thread -> (k row bkk, col lane bj); 16 scalar fp32->bf16
    const int bkk = tid >> 3, bj = tid & 7;
    const float* bbase = gup + ((size_t)e << 21) + (size_t)bkk * 2048;

    const int lane = tid & 63, wv = tid >> 6;
    const int fm = lane & 15, kg = lane >> 4;

    f32x4 accg[2][4], accu[2][4];
#pragma unroll
    for (int mt = 0; mt < 2; ++mt)
#pragma unroll
        for (int nt = 0; nt < 4; ++nt) {
            accg[mt][nt] = (f32x4){0.f, 0.f, 0.f, 0.f};
            accu[mt][nt] = (f32x4){0.f, 0.f, 0.f, 0.f};
        }

    for (int k0 = 0; k0 < H_DIM; k0 += 32) {
        __syncthreads();
        *(uint4*)asdst       = *(const uint4*)(arow + k0);
        *(uint4*)(asdst + 8) = *(const uint4*)(arow + k0 + 8);
        const float* bsrc = bbase + (size_t)k0 * 2048;
#pragma unroll
        for (int i = 0; i < 16; ++i) {
            int j = bj + i * 8;
            int col = (j < 64) ? (n0 + j) : (960 + n0 + j); // up half at 1024+
            Bs[j * 40 + bkk] = f2bf(bsrc[col]);
        }
        __syncthreads();

        bf16x8 af0 = *(const bf16x8*)&As[(wv * 32 + fm) * 40 + kg * 8];
        bf16x8 af1 = *(const bf16x8*)&As[(wv * 32 + 16 + fm) * 40 + kg * 8];
#pragma unroll
        for (int nt = 0; nt < 4; ++nt) {
            bf16x8 bg = *(const bf16x8*)&Bs[(nt * 16 + fm) * 40 + kg * 8];
            bf16x8 bu = *(const bf16x8*)&Bs[(64 + nt * 16 + fm) * 40 + kg * 8];
            accg[0][nt] = mfma16(af0, bg, accg[0][nt]);
            accg[1][nt] = mfma16(af1, bg, accg[1][nt]);
            accu[0][nt] = mfma16(af0, bu, accu[0][nt]);
            accu[1][nt] = mfma16(af1, bu, accu[1][nt]);
        }
    }

    // epilogue: bias + clamped GLU, write compact bf16 act rows
#pragma unroll
    for (int mt = 0; mt < 2; ++mt) {
#pragma unroll
        for (int r = 0; r < 4; ++r) {
            int rowb = wv * 32 + mt * 16 + kg * 4 + r; // C/D: row=(lane>>4)*4+reg
            int slot = m0 + rowb;
            if (slot >= cnt) continue;
            size_t arow_o = (size_t)(abase + slot) * I_DIM;
#pragma unroll
            for (int nt = 0; nt < 4; ++nt) {
                int cn = n0 + nt * 16 + fm;           // C/D: col=lane&15
                float g = accg[mt][nt][r] + gub[e * 2048 + cn];
                float u = accu[mt][nt][r] + gub[e * 2048 + 1024 + cn];
                g = fminf(g, LIMIT);
                u = fminf(fmaxf(u, -LIMIT), LIMIT);
                float glu = g / (1.f + __expf(-ALPHA * g));
                act[arow_o + cn] = f2bf((u + 1.f) * glu);
            }
        }
    }
}

// --------------------------- K4: down GEMM * router weight ------------------
__global__ __launch_bounds__(256, 2) void k_down(
    const float* __restrict__ dp,
    const int* __restrict__ counts, const int* __restrict__ ebase,
    const float* __restrict__ w_list,
    const u16* __restrict__ act, float* __restrict__ dout)
{
    const int e = blockIdx.z;
    const int cnt = counts[e];
    const int m0 = blockIdx.y * 128;
    if (m0 >= cnt) return;
    const int n0 = blockIdx.x * 64;
    const int abase = ebase[e];
    const int tid = threadIdx.x;

    __shared__ __align__(16) u16 As[128 * 40];
    __shared__ __align__(16) u16 Bs[64 * 40];

    const int am = tid >> 1, akq = tid & 1;
    // rows past cnt read other/slack rows (finite garbage), masked at store
    const u16* arow = act + (size_t)(abase + m0 + am) * I_DIM + akq * 16;
    u16* asdst = &As[am * 40 + akq * 16];

    const int bkk = tid >> 3, bj = tid & 7;
    const float* bbase = dp + ((size_t)e << 20) + (size_t)bkk * 1024 + n0;

    const int lane = tid & 63, wv = tid >> 6;
    const int fm = lane & 15, kg = lane >> 4;

    f32x4 acc[2][4];
#pragma unroll
    for (int mt = 0; mt < 2; ++mt)
#pragma unroll
        for (int nt = 0; nt < 4; ++nt) acc[mt][nt] = (f32x4){0.f, 0.f, 0.f, 0.f};

    for (int k0 = 0; k0 < I_DIM; k0 += 32) {
        __syncthreads();
        *(uint4*)asdst       = *(const uint4*)(arow + k0);
        *(uint4*)(asdst + 8) = *(const uint4*)(arow + k0 + 8);
        const float* bsrc = bbase + (size_t)k0 * 1024;
#pragma unroll
        for (int i = 0; i < 8; ++i) {
            int j = bj + i * 8;
            Bs[j * 40 + bkk] = f2bf(bsrc[j]);
        }
        __syncthreads();

        bf16x8 af0 = *(const bf16x8*)&As[(wv * 32 + fm) * 40 + kg * 8];
        bf16x8 af1 = *(const bf16x8*)&As[(wv * 32 + 16 + fm) * 40 + kg * 8];
#pragma unroll
        for (int nt = 0; nt < 4; ++nt) {
            bf16x8 b = *(const bf16x8*)&Bs[(nt * 16 + fm) * 40 + kg * 8];
            acc[0][nt] = mfma16(af0, b, acc[0][nt]);
            acc[1][nt] = mfma16(af1, b, acc[1][nt]);
        }
    }

#pragma unroll
    for (int mt = 0; mt < 2; ++mt) {
#pragma unroll
        for (int r = 0; r < 4; ++r) {
            int rowb = wv * 32 + mt * 16 + kg * 4 + r;
            int slot = m0 + rowb;
            if (slot >= cnt) continue;
            float wgt = w_list[e * T_TOK + slot];
            size_t drow = (size_t)(abase + slot) * H_DIM;
#pragma unroll
            for (int nt = 0; nt < 4; ++nt)
                dout[drow + n0 + nt * 16 + fm] = acc[mt][nt][r] * wgt;
        }
    }
}

// --------------------------- K5: combine pairs + weighted bias --------------
__global__ __launch_bounds__(256) void k_combine(
    const float* __restrict__ dout, const float* __restrict__ db,
    const int* __restrict__ tk_e, const int* __restrict__ tk_slot,
    const float* __restrict__ tk_w, const int* __restrict__ ebase,
    float* __restrict__ out)
{
    const int t = blockIdx.x, tid = threadIdx.x;
    const int e0 = tk_e[t * 2], e1 = tk_e[t * 2 + 1];
    const int p0 = ebase[e0] + tk_slot[t * 2];
    const int p1 = ebase[e1] + tk_slot[t * 2 + 1];
    const float w0 = tk_w[t * 2], w1 = tk_w[t * 2 + 1];
    const int c = tid * 4;
    float4 a  = *(const float4*)(dout + (size_t)p0 * H_DIM + c);
    float4 b  = *(const float4*)(dout + (size_t)p1 * H_DIM + c);
    float4 d0 = *(const float4*)(db + e0 * H_DIM + c);
    float4 d1 = *(const float4*)(db + e1 * H_DIM + c);
    float4 o;
    o.x = a.x + b.x + w0 * d0.x + w1 * d1.x;
    o.y = a.y + b.y + w0 * d0.y + w1 * d1.y;
    o.z = a.z + b.z + w0 * d0.z + w1 * d1.z;
    o.w = a.w + b.w + w0 * d0.w + w1 * d1.w;
    *(float4*)(out + (size_t)t * H_DIM + c) = o;
}

// ---------------------------------------------------------------------------
extern "C" void kernel_launch(void* const* d_in, const int* in_sizes, int n_in,
                              void* d_out, int out_size, void* d_ws, size_t ws_size,
                              hipStream_t stream) {
    const float* x   = (const float*)d_in[0]; // [1,1024,1024]
    const float* rw  = (const float*)d_in[1]; // [8,1024]
    const float* rb  = (const float*)d_in[2]; // [8]
    const float* gup = (const float*)d_in[3]; // [8,1024,2048]
    const float* gub = (const float*)d_in[4]; // [8,2048]
    const float* dp  = (const float*)d_in[5]; // [8,1024,1024]
    const float* db  = (const float*)d_in[6]; // [8,1024]
    float* out = (float*)d_out;

    char* ws = (char*)d_ws;
    int*   counts   = (int*)(ws);                       // 8 ints
    int*   ebase    = (int*)(ws + 32);                  // 8 ints
    int*   tk_e     = (int*)(ws + 64);                  // 2048
    int*   tk_slot  = (int*)(ws + 64 + 8192);           // 2048
    float* tk_w     = (float*)(ws + 64 + 16384);        // 2048
    int*   tok_list = (int*)(ws + 64 + 24576);          // 8*1024
    float* w_list   = (float*)(ws + 64 + 24576 + 32768);// 8*1024
    u16*   xb       = (u16*)(ws + 90368);               // 1024*1024 bf16 (2 MB)
    u16*   act      = (u16*)(ws + 90368 + 2097152);     // 2176*1024 bf16 (4.25 MB)
    float* dout     = (float*)(ws + 90368 + 2097152 + 2176 * 1024 * 2); // 2176*1024 f32

    k_zero<<<1, 64, 0, stream>>>(counts);
    k_router<<<T_TOK, 256, 0, stream>>>(x, rw, rb, counts, tk_e, tk_slot, tk_w,
                                        tok_list, w_list, xb);
    k_prefix<<<1, 64, 0, stream>>>(counts, ebase);
    k_gateup<<<dim3(16, 8, 8), 256, 0, stream>>>(gup, gub, counts, ebase,
                                                 tok_list, xb, act);
    k_down<<<dim3(16, 8, 8), 256, 0, stream>>>(dp, counts, ebase, w_list, act, dout);
    k_combine<<<T_TOK, 256, 0, stream>>>(dout, db, tk_e, tk_slot, tk_w, ebase, out);
}

// Round 2
// 286.963 us; speedup vs baseline: 1.0478x; 1.0478x over previous
//
#include <hip/hip_runtime.h>
#include <hip/hip_bf16.h>

// ---------------------------------------------------------------------------
// SingleLayerMoE: T=1024 tokens, H=1024, E=8 experts, I=1024, top-2 routing.
// Sparse dispatch: router -> per-expert token lists -> per-expert MFMA GEMMs
// (gate_up + GLU, then down * router_weight) -> combine.
// R1: vectorized float4 B staging + register double-buffer + BN=32 (2 blk/CU).
// ---------------------------------------------------------------------------

typedef unsigned short u16;
typedef __attribute__((ext_vector_type(8))) __bf16 bf16x8;
typedef __attribute__((ext_vector_type(4))) float f32x4;

#define T_TOK 1024
#define H_DIM 1024
#define E_NUM 8
#define I_DIM 1024
#define ALPHA 1.702f
#define LIMIT 7.0f

// round-to-nearest-even fp32 -> bf16 (no NaN in this workload)
__device__ __forceinline__ u16 f2bf(float f) {
    unsigned u = __builtin_bit_cast(unsigned, f);
    u = (u + 0x7FFFu + ((u >> 16) & 1u)) >> 16;
    return (u16)u;
}

__device__ __forceinline__ f32x4 mfma16(bf16x8 a, bf16x8 b, f32x4 c) {
    return __builtin_amdgcn_mfma_f32_16x16x32_bf16(a, b, c, 0, 0, 0);
}

// --------------------------- K0: zero counters ------------------------------
__global__ void k_zero(int* counts) {
    if (threadIdx.x < E_NUM) counts[threadIdx.x] = 0;
}

// --------------------------- K1: router + dispatch + x->bf16 ----------------
// one block (256 thr) per token
__global__ __launch_bounds__(256) void k_router(
    const float* __restrict__ x, const float* __restrict__ rw,
    const float* __restrict__ rb,
    int* __restrict__ counts, int* __restrict__ tk_e, int* __restrict__ tk_slot,
    float* __restrict__ tk_w, int* __restrict__ tok_list,
    float* __restrict__ w_list, u16* __restrict__ xb)
{
    const int t = blockIdx.x;
    const int tid = threadIdx.x;
    const float4 xv = *(const float4*)(x + (size_t)t * H_DIM + tid * 4);

    // store bf16 copy of the hidden state (A operand for gate_up GEMM)
    unsigned lo = (unsigned)f2bf(xv.x) | ((unsigned)f2bf(xv.y) << 16);
    unsigned hi = (unsigned)f2bf(xv.z) | ((unsigned)f2bf(xv.w) << 16);
    *(uint2*)(xb + (size_t)t * H_DIM + tid * 4) = make_uint2(lo, hi);

    // partial logits for all 8 experts (fp32 — must match np top-k closely)
    float p[E_NUM];
#pragma unroll
    for (int e = 0; e < E_NUM; ++e) {
        const float4 wv = *(const float4*)(rw + e * H_DIM + tid * 4);
        p[e] = xv.x * wv.x + xv.y * wv.y + xv.z * wv.z + xv.w * wv.w;
    }
#pragma unroll
    for (int off = 32; off; off >>= 1) {
#pragma unroll
        for (int e = 0; e < E_NUM; ++e) p[e] += __shfl_down(p[e], off, 64);
    }
    __shared__ float red[4][E_NUM];
    const int lane = tid & 63, wvid = tid >> 6;
    if (lane == 0) {
#pragma unroll
        for (int e = 0; e < E_NUM; ++e) red[wvid][e] = p[e];
    }
    __syncthreads();
    if (tid == 0) {
        float lg[E_NUM];
#pragma unroll
        for (int e = 0; e < E_NUM; ++e)
            lg[e] = red[0][e] + red[1][e] + red[2][e] + red[3][e] + rb[e];
        // top-2 (first index wins ties, matching lax.top_k)
        float m1 = -1e30f, m2 = -1e30f; int i1 = 0, i2 = 0;
#pragma unroll
        for (int e = 0; e < E_NUM; ++e) {
            float l = lg[e];
            if (l > m1) { m2 = m1; i2 = i1; m1 = l; i1 = e; }
            else if (l > m2) { m2 = l; i2 = e; }
        }
        float s = 0.f;
#pragma unroll
        for (int e = 0; e < E_NUM; ++e) s += __expf(lg[e] - m1);
        const float w0 = 1.0f / s;
        const float w1 = __expf(m2 - m1) / s;
        int ee[2] = { i1, i2 };
        float ww[2] = { w0, w1 };
#pragma unroll
        for (int k = 0; k < 2; ++k) {
            int e = ee[k];
            int slot = atomicAdd(&counts[e], 1);
            tok_list[e * T_TOK + slot] = t;
            w_list[e * T_TOK + slot] = ww[k];
            tk_e[t * 2 + k] = e;
            tk_slot[t * 2 + k] = slot;
            tk_w[t * 2 + k] = ww[k];
        }
    }
}

// --------------------------- K2: prefix over 8 counts -----------------------
__global__ void k_prefix(const int* __restrict__ counts, int* __restrict__ ebase) {
    if (threadIdx.x == 0) {
        int a = 0;
        for (int e = 0; e < E_NUM; ++e) { ebase[e] = a; a += counts[e]; }
    }
}

// --------------------------- K3: gate_up GEMM + GLU -------------------------
// grid (32 strips of 32 act cols, 8 m-tiles of 128 rows, 8 experts)
// B tile per k-step: 64 LDS cols (0..31 gate, 32..63 up) x 32 k.
__global__ __launch_bounds__(256) void k_gateup(
    const float* __restrict__ gup, const float* __restrict__ gub,
    const int* __restrict__ counts, const int* __restrict__ ebase,
    const int* __restrict__ tok_list, const u16* __restrict__ xb,
    u16* __restrict__ act)
{
    const int e = blockIdx.z;
    const int cnt = counts[e];
    const int m0 = blockIdx.y * 128;
    if (m0 >= cnt) return;
    const int n0 = blockIdx.x * 32;
    const int abase = ebase[e];
    const int tid = threadIdx.x;

    // stride 40 u16 (80 B): 16B-granule slots (5*col+kg) mod 8 are uniform ->
    // ds_read_b128 fragment reads conflict-free (verified R0: conflicts 0.04%)
    __shared__ __align__(16) u16 As[128 * 40];
    __shared__ __align__(16) u16 Bs[64 * 40];

    // A staging: thread -> (row, 16-elem k chunk), bf16 source (L2-resident)
    const int am = tid >> 1, akq = tid & 1;
    const int aslot = m0 + am;
    const int atok = (aslot < cnt) ? tok_list[e * T_TOK + aslot] : 0;
    const u16* arow = xb + (size_t)atok * H_DIM + akq * 16;
    u16* asdst = &As[am * 40 + akq * 16];

    // B staging: thread -> (k-row kk, 4-col quad cg); 2 coalesced float4 loads
    const int kk = tid >> 3, cg = tid & 7;
    const float* bgate = gup + ((size_t)e << 21) + (size_t)kk * 2048 + n0 + cg * 4;
    const float* bup   = bgate + 1024;
    u16* bdg = &Bs[(cg * 4) * 40 + kk];
    u16* bdu = &Bs[(32 + cg * 4) * 40 + kk];

    const int lane = tid & 63, wv = tid >> 6;
    const int fm = lane & 15, kg = lane >> 4;

    f32x4 accg[2][2], accu[2][2];
#pragma unroll
    for (int mt = 0; mt < 2; ++mt)
#pragma unroll
        for (int nt = 0; nt < 2; ++nt) {
            accg[mt][nt] = (f32x4){0.f, 0.f, 0.f, 0.f};
            accu[mt][nt] = (f32x4){0.f, 0.f, 0.f, 0.f};
        }

    // register double-buffer: preload k-step 0
    uint4  ra0 = *(const uint4*)(arow);
    uint4  ra1 = *(const uint4*)(arow + 8);
    float4 rbg = *(const float4*)(bgate);
    float4 rbu = *(const float4*)(bup);

    for (int k0 = 0; k0 < H_DIM; k0 += 32) {
        __syncthreads();
        *(uint4*)asdst       = ra0;
        *(uint4*)(asdst + 8) = ra1;
        bdg[0]  = f2bf(rbg.x); bdg[40]  = f2bf(rbg.y);
        bdg[80] = f2bf(rbg.z); bdg[120] = f2bf(rbg.w);
        bdu[0]  = f2bf(rbu.x); bdu[40]  = f2bf(rbu.y);
        bdu[80] = f2bf(rbu.z); bdu[120] = f2bf(rbu.w);
        if (k0 + 32 < H_DIM) {   // prefetch next k-step; latency hidden by MFMA
            ra0 = *(const uint4*)(arow + k0 + 32);
            ra1 = *(const uint4*)(arow + k0 + 40);
            rbg = *(const float4*)(bgate + (size_t)(k0 + 32) * 2048);
            rbu = *(const float4*)(bup   + (size_t)(k0 + 32) * 2048);
        }
        __syncthreads();

        bf16x8 af0 = *(const bf16x8*)&As[(wv * 32 + fm) * 40 + kg * 8];
        bf16x8 af1 = *(const bf16x8*)&As[(wv * 32 + 16 + fm) * 40 + kg * 8];
#pragma unroll
        for (int nt = 0; nt < 2; ++nt) {
            bf16x8 bgf = *(const bf16x8*)&Bs[(nt * 16 + fm) * 40 + kg * 8];
            bf16x8 buf = *(const bf16x8*)&Bs[(32 + nt * 16 + fm) * 40 + kg * 8];
            accg[0][nt] = mfma16(af0, bgf, accg[0][nt]);
            accg[1][nt] = mfma16(af1, bgf, accg[1][nt]);
            accu[0][nt] = mfma16(af0, buf, accu[0][nt]);
            accu[1][nt] = mfma16(af1, buf, accu[1][nt]);
        }
    }

    // epilogue: bias + clamped GLU, write compact bf16 act rows
#pragma unroll
    for (int mt = 0; mt < 2; ++mt) {
#pragma unroll
        for (int r = 0; r < 4; ++r) {
            int rowb = wv * 32 + mt * 16 + kg * 4 + r; // C/D: row=(lane>>4)*4+reg
            int slot = m0 + rowb;
            if (slot >= cnt) continue;
            size_t arow_o = (size_t)(abase + slot) * I_DIM;
#pragma unroll
            for (int nt = 0; nt < 2; ++nt) {
                int cn = n0 + nt * 16 + fm;           // C/D: col=lane&15
                float g = accg[mt][nt][r] + gub[e * 2048 + cn];
                float u = accu[mt][nt][r] + gub[e * 2048 + 1024 + cn];
                g = fminf(g, LIMIT);
                u = fminf(fmaxf(u, -LIMIT), LIMIT);
                float glu = g / (1.f + __expf(-ALPHA * g));
                act[arow_o + cn] = f2bf((u + 1.f) * glu);
            }
        }
    }
}

// --------------------------- K4: down GEMM * router weight ------------------
// grid (32 strips of 32 H cols, 8 m-tiles of 128 rows, 8 experts)
__global__ __launch_bounds__(256) void k_down(
    const float* __restrict__ dp,
    const int* __restrict__ counts, const int* __restrict__ ebase,
    const float* __restrict__ w_list,
    const u16* __restrict__ act, float* __restrict__ dout)
{
    const int e = blockIdx.z;
    const int cnt = counts[e];
    const int m0 = blockIdx.y * 128;
    if (m0 >= cnt) return;
    const int n0 = blockIdx.x * 32;
    const int abase = ebase[e];
    const int tid = threadIdx.x;

    __shared__ __align__(16) u16 As[128 * 40];
    __shared__ __align__(16) u16 Bs[32 * 40];

    const int am = tid >> 1, akq = tid & 1;
    // rows past cnt read slack rows (finite 0xAAAA garbage), masked at store
    const u16* arow = act + (size_t)(abase + m0 + am) * I_DIM + akq * 16;
    u16* asdst = &As[am * 40 + akq * 16];

    const int kk = tid >> 3, cg = tid & 7;
    const float* bsrc = dp + ((size_t)e << 20) + (size_t)kk * 1024 + n0 + cg * 4;
    u16* bd = &Bs[(cg * 4) * 40 + kk];

    const int lane = tid & 63, wv = tid >> 6;
    const int fm = lane & 15, kg = lane >> 4;

    f32x4 acc[2][2];
#pragma unroll
    for (int mt = 0; mt < 2; ++mt)
#pragma unroll
        for (int nt = 0; nt < 2; ++nt) acc[mt][nt] = (f32x4){0.f, 0.f, 0.f, 0.f};

    uint4  ra0 = *(const uint4*)(arow);
    uint4  ra1 = *(const uint4*)(arow + 8);
    float4 rb  = *(const float4*)(bsrc);

    for (int k0 = 0; k0 < I_DIM; k0 += 32) {
        __syncthreads();
        *(uint4*)asdst       = ra0;
        *(uint4*)(asdst + 8) = ra1;
        bd[0]  = f2bf(rb.x); bd[40]  = f2bf(rb.y);
        bd[80] = f2bf(rb.z); bd[120] = f2bf(rb.w);
        if (k0 + 32 < I_DIM) {
            ra0 = *(const uint4*)(arow + k0 + 32);
            ra1 = *(const uint4*)(arow + k0 + 40);
            rb  = *(const float4*)(bsrc + (size_t)(k0 + 32) * 1024);
        }
        __syncthreads();

        bf16x8 af0 = *(const bf16x8*)&As[(wv * 32 + fm) * 40 + kg * 8];
        bf16x8 af1 = *(const bf16x8*)&As[(wv * 32 + 16 + fm) * 40 + kg * 8];
#pragma unroll
        for (int nt = 0; nt < 2; ++nt) {
            bf16x8 b = *(const bf16x8*)&Bs[(nt * 16 + fm) * 40 + kg * 8];
            acc[0][nt] = mfma16(af0, b, acc[0][nt]);
            acc[1][nt] = mfma16(af1, b, acc[1][nt]);
        }
    }

#pragma unroll
    for (int mt = 0; mt < 2; ++mt) {
#pragma unroll
        for (int r = 0; r < 4; ++r) {
            int rowb = wv * 32 + mt * 16 + kg * 4 + r;
            int slot = m0 + rowb;
            if (slot >= cnt) continue;
            float wgt = w_list[e * T_TOK + slot];
            size_t drow = (size_t)(abase + slot) * H_DIM;
#pragma unroll
            for (int nt = 0; nt < 2; ++nt)
                dout[drow + n0 + nt * 16 + fm] = acc[mt][nt][r] * wgt;
        }
    }
}

// --------------------------- K5: combine pairs + weighted bias --------------
__global__ __launch_bounds__(256) void k_combine(
    const float* __restrict__ dout, const float* __restrict__ db,
    const int* __restrict__ tk_e, const int* __restrict__ tk_slot,
    const float* __restrict__ tk_w, const int* __restrict__ ebase,
    float* __restrict__ out)
{
    const int t = blockIdx.x, tid = threadIdx.x;
    const int e0 = tk_e[t * 2], e1 = tk_e[t * 2 + 1];
    const int p0 = ebase[e0] + tk_slot[t * 2];
    const int p1 = ebase[e1] + tk_slot[t * 2 + 1];
    const float w0 = tk_w[t * 2], w1 = tk_w[t * 2 + 1];
    const int c = tid * 4;
    float4 a  = *(const float4*)(dout + (size_t)p0 * H_DIM + c);
    float4 b  = *(const float4*)(dout + (size_t)p1 * H_DIM + c);
    float4 d0 = *(const float4*)(db + e0 * H_DIM + c);
    float4 d1 = *(const float4*)(db + e1 * H_DIM + c);
    float4 o;
    o.x = a.x + b.x + w0 * d0.x + w1 * d1.x;
    o.y = a.y + b.y + w0 * d0.y + w1 * d1.y;
    o.z = a.z + b.z + w0 * d0.z + w1 * d1.z;
    o.w = a.w + b.w + w0 * d0.w + w1 * d1.w;
    *(float4*)(out + (size_t)t * H_DIM + c) = o;
}

// ---------------------------------------------------------------------------
extern "C" void kernel_launch(void* const* d_in, const int* in_sizes, int n_in,
                              void* d_out, int out_size, void* d_ws, size_t ws_size,
                              hipStream_t stream) {
    const float* x   = (const float*)d_in[0]; // [1,1024,1024]
    const float* rw  = (const float*)d_in[1]; // [8,1024]
    const float* rb  = (const float*)d_in[2]; // [8]
    const float* gup = (const float*)d_in[3]; // [8,1024,2048]
    const float* gub = (const float*)d_in[4]; // [8,2048]
    const float* dp  = (const float*)d_in[5]; // [8,1024,1024]
    const float* db  = (const float*)d_in[6]; // [8,1024]
    float* out = (float*)d_out;

    char* ws = (char*)d_ws;
    int*   counts   = (int*)(ws);                       // 8 ints
    int*   ebase    = (int*)(ws + 32);                  // 8 ints
    int*   tk_e     = (int*)(ws + 64);                  // 2048
    int*   tk_slot  = (int*)(ws + 64 + 8192);           // 2048
    float* tk_w     = (float*)(ws + 64 + 16384);        // 2048
    int*   tok_list = (int*)(ws + 64 + 24576);          // 8*1024
    float* w_list   = (float*)(ws + 64 + 24576 + 32768);// 8*1024
    u16*   xb       = (u16*)(ws + 90368);               // 1024*1024 bf16 (2 MB)
    u16*   act      = (u16*)(ws + 90368 + 2097152);     // 2176*1024 bf16 (4.25 MB)
    float* dout     = (float*)(ws + 90368 + 2097152 + 2176 * 1024 * 2); // 2176*1024 f32

    k_zero<<<1, 64, 0, stream>>>(counts);
    k_router<<<T_TOK, 256, 0, stream>>>(x, rw, rb, counts, tk_e, tk_slot, tk_w,
                                        tok_list, w_list, xb);
    k_prefix<<<1, 64, 0, stream>>>(counts, ebase);
    k_gateup<<<dim3(32, 8, 8), 256, 0, stream>>>(gup, gub, counts, ebase,
                                                 tok_list, xb, act);
    k_down<<<dim3(32, 8, 8), 256, 0, stream>>>(dp, counts, ebase, w_list, act, dout);
    k_combine<<<T_TOK, 256, 0, stream>>>(dout, db, tk_e, tk_slot, tk_w, ebase, out);
}